// Round 1
// baseline (189.179 us; speedup 1.0000x reference)
//
#include <hip/hip_runtime.h>

// RoIAlign forward, aligned=True, sampling_ratio=2, pooled 7x7, scale 0.25.
// x: [B,C,H,W] f32, rois: [K,5] f32 (bidx,x1,y1,x2,y2), out: [K,C,7,7] f32.

#define PH 7
#define PW 7
#define SCALE 0.25f

__device__ __forceinline__ void axis_sample(float coord, int limit,
                                            int& lo, int& hi,
                                            float& w0, float& w1) {
    float fl = (float)limit;
    float valid = (coord >= -1.0f && coord <= fl) ? 1.0f : 0.0f;
    float c = fmaxf(coord, 0.0f);
    int low0 = (int)floorf(c);
    bool cap = low0 >= limit - 1;
    lo = cap ? limit - 1 : low0;
    hi = cap ? limit - 1 : low0 + 1;
    c = cap ? (float)lo : c;
    float l = c - (float)lo;
    w1 = l * valid;
    w0 = (1.0f - l) * valid;
}

__global__ void __launch_bounds__(256)
roi_align_kernel(const float* __restrict__ x, const float* __restrict__ rois,
                 float* __restrict__ out, int total, int C, int H, int W) {
    int idx = blockIdx.x * blockDim.x + threadIdx.x;
    if (idx >= total) return;

    int pw = idx % PW;
    int ph = (idx / PW) % PH;
    int c  = (idx / (PW * PH)) % C;
    int k  = idx / (PW * PH * C);

    const float* r = rois + (size_t)k * 5;
    int b = (int)r[0];
    float start_w = r[1] * SCALE - 0.5f;
    float start_h = r[2] * SCALE - 0.5f;
    float end_w   = r[3] * SCALE - 0.5f;
    float end_h   = r[4] * SCALE - 0.5f;
    float bin_w = (end_w - start_w) / (float)PW;
    float bin_h = (end_h - start_h) / (float)PH;

    const float* xp = x + ((size_t)b * C + c) * (size_t)(H * W);

    float acc = 0.0f;
#pragma unroll
    for (int sy = 0; sy < 2; ++sy) {
        float yc = start_h + ((float)ph + (sy + 0.5f) * 0.5f) * bin_h;
        int yl, yh; float wy0, wy1;
        axis_sample(yc, H, yl, yh, wy0, wy1);
        const float* row0 = xp + (size_t)yl * W;
        const float* row1 = xp + (size_t)yh * W;
#pragma unroll
        for (int sx = 0; sx < 2; ++sx) {
            float xc = start_w + ((float)pw + (sx + 0.5f) * 0.5f) * bin_w;
            int xl, xh; float wx0, wx1;
            axis_sample(xc, W, xl, xh, wx0, wx1);
            float v00 = row0[xl];
            float v01 = row0[xh];
            float v10 = row1[xl];
            float v11 = row1[xh];
            acc += wy0 * (wx0 * v00 + wx1 * v01) + wy1 * (wx0 * v10 + wx1 * v11);
        }
    }
    out[idx] = acc * 0.25f;
}

extern "C" void kernel_launch(void* const* d_in, const int* in_sizes, int n_in,
                              void* d_out, int out_size, void* d_ws, size_t ws_size,
                              hipStream_t stream) {
    const float* x    = (const float*)d_in[0];
    const float* rois = (const float*)d_in[1];
    float* out = (float*)d_out;

    const int C = 256, H = 200, W = 200;
    int K = in_sizes[1] / 5;
    int total = K * C * PH * PW;

    int block = 256;
    int grid = (total + block - 1) / block;
    roi_align_kernel<<<grid, block, 0, stream>>>(x, rois, out, total, C, H, W);
}

// Round 2
// 107.661 us; speedup vs baseline: 1.7572x; 1.7572x over previous
//
#include <hip/hip_runtime.h>
#include <hip/hip_bf16.h>

// RoIAlign forward, aligned=True, sampling_ratio=2, pooled 7x7, scale 0.25.
// Strategy: (1) transpose x [B,C,H,W] f32 -> xt [B,H*W,C] bf16 (channels-last,
// coalesced gathers), (2) one block per ROI, per-ROI bilinear tables in LDS,
// each thread owns 8 consecutive channels -> every corner gather is a 16B
// uint4 load, fully coalesced across the wave.

#define PH 7
#define PW 7
#define SCALE 0.25f
#define C_ 256
#define H_ 200
#define W_ 200
#define HW_ (H_ * W_)

// ---------------- transpose: x [B,C,HW] f32 -> xt [B,HW,C] bf16 --------------
__global__ void __launch_bounds__(512)
transpose_kernel(const float* __restrict__ x, __hip_bfloat16* __restrict__ xt) {
    __shared__ float tile[64][65];
    int hw0 = blockIdx.x * 64;
    int c0  = blockIdx.y * 64;
    int b   = blockIdx.z;
    int tx = threadIdx.x;   // 0..63
    int ty = threadIdx.y;   // 0..7
    const float* xb = x + (size_t)b * C_ * HW_;
#pragma unroll
    for (int j = 0; j < 8; ++j) {
        int cl = ty + 8 * j;
        tile[cl][tx] = xb[(size_t)(c0 + cl) * HW_ + hw0 + tx];
    }
    __syncthreads();
    __hip_bfloat16* xtb = xt + (size_t)b * HW_ * C_;
#pragma unroll
    for (int j = 0; j < 8; ++j) {
        int rl = ty + 8 * j;   // hw-local
        float v = tile[tx][rl];
        xtb[(size_t)(hw0 + rl) * C_ + c0 + tx] = __float2bfloat16(v);
    }
}

// ---------------- main: one block (256 thr) per ROI --------------------------
__global__ void __launch_bounds__(256)
roi_main(const __hip_bfloat16* __restrict__ xt, const float* __restrict__ rois,
         float* __restrict__ out, int K) {
    __shared__ int   s_ylo[14], s_yhi[14], s_xlo[14], s_xhi[14];
    __shared__ float s_wy0[14], s_wy1[14], s_wx0[14], s_wx1[14];
    __shared__ int   s_b;

    int k = blockIdx.x;
    int t = threadIdx.x;
    const float* r = rois + (size_t)k * 5;
    if (t == 0) s_b = (int)r[0];
    if (t < 28) {
        bool isy = t < 14;
        int i = isy ? t : t - 14;
        float start = (isy ? r[2] : r[1]) * SCALE - 0.5f;
        float end   = (isy ? r[4] : r[3]) * SCALE - 0.5f;
        float bin = (end - start) * (1.0f / 7.0f);
        int limit = isy ? H_ : W_;
        float pp   = (float)(i >> 1);
        float soff = (i & 1) ? 0.75f : 0.25f;
        float coord = fmaf(pp + soff, bin, start);
        float valid = (coord >= -1.0f && coord <= (float)limit) ? 1.0f : 0.0f;
        float cc = fmaxf(coord, 0.0f);
        int low0 = (int)floorf(cc);
        bool cap = low0 >= limit - 1;
        int lo = cap ? limit - 1 : low0;
        int hi = cap ? limit - 1 : low0 + 1;
        cc = cap ? (float)lo : cc;
        float l = cc - (float)lo;
        float w1 = l * valid, w0 = (1.0f - l) * valid;
        if (isy) { s_ylo[i] = lo; s_yhi[i] = hi; s_wy0[i] = w0; s_wy1[i] = w1; }
        else     { s_xlo[i] = lo; s_xhi[i] = hi; s_wx0[i] = w0; s_wx1[i] = w1; }
    }
    __syncthreads();

    int cg = t & 31;     // channel group: channels 8*cg .. 8*cg+7
    int pq = t >> 5;     // 0..7 -> handles p = pq, pq+8, ...

    const __hip_bfloat16* xb = xt + (size_t)s_b * HW_ * C_ + cg * 8;
    float* outk = out + ((size_t)k * C_ + cg * 8) * 49;

    for (int p = pq; p < 49; p += 8) {
        int ph = p / 7;
        int pw = p - ph * 7;
        float acc[8];
#pragma unroll
        for (int j = 0; j < 8; ++j) acc[j] = 0.0f;

#pragma unroll
        for (int sy = 0; sy < 2; ++sy) {
            int ys = 2 * ph + sy;
            int yl = s_ylo[ys], yh = s_yhi[ys];
            float wy0 = s_wy0[ys], wy1 = s_wy1[ys];
#pragma unroll
            for (int sx = 0; sx < 2; ++sx) {
                int xs = 2 * pw + sx;
                int xl = s_xlo[xs], xh = s_xhi[xs];
                float wx0 = s_wx0[xs], wx1 = s_wx1[xs];
                float w00 = wy0 * wx0, w01 = wy0 * wx1;
                float w10 = wy1 * wx0, w11 = wy1 * wx1;
                uint4 v00 = *(const uint4*)(xb + ((size_t)(yl * W_ + xl) << 8));
                uint4 v01 = *(const uint4*)(xb + ((size_t)(yl * W_ + xh) << 8));
                uint4 v10 = *(const uint4*)(xb + ((size_t)(yh * W_ + xl) << 8));
                uint4 v11 = *(const uint4*)(xb + ((size_t)(yh * W_ + xh) << 8));
                const unsigned* a00 = (const unsigned*)&v00;
                const unsigned* a01 = (const unsigned*)&v01;
                const unsigned* a10 = (const unsigned*)&v10;
                const unsigned* a11 = (const unsigned*)&v11;
#pragma unroll
                for (int w = 0; w < 4; ++w) {
                    float f00l = __uint_as_float(a00[w] << 16);
                    float f00h = __uint_as_float(a00[w] & 0xffff0000u);
                    float f01l = __uint_as_float(a01[w] << 16);
                    float f01h = __uint_as_float(a01[w] & 0xffff0000u);
                    float f10l = __uint_as_float(a10[w] << 16);
                    float f10h = __uint_as_float(a10[w] & 0xffff0000u);
                    float f11l = __uint_as_float(a11[w] << 16);
                    float f11h = __uint_as_float(a11[w] & 0xffff0000u);
                    acc[2 * w]     = fmaf(w00, f00l, acc[2 * w]);
                    acc[2 * w]     = fmaf(w01, f01l, acc[2 * w]);
                    acc[2 * w]     = fmaf(w10, f10l, acc[2 * w]);
                    acc[2 * w]     = fmaf(w11, f11l, acc[2 * w]);
                    acc[2 * w + 1] = fmaf(w00, f00h, acc[2 * w + 1]);
                    acc[2 * w + 1] = fmaf(w01, f01h, acc[2 * w + 1]);
                    acc[2 * w + 1] = fmaf(w10, f10h, acc[2 * w + 1]);
                    acc[2 * w + 1] = fmaf(w11, f11h, acc[2 * w + 1]);
                }
            }
        }
#pragma unroll
        for (int j = 0; j < 8; ++j) outk[(size_t)j * 49 + p] = acc[j] * 0.25f;
    }
}

// ---------------- fallback (round-1 kernel) if ws too small ------------------
__device__ __forceinline__ void axis_sample(float coord, int limit,
                                            int& lo, int& hi,
                                            float& w0, float& w1) {
    float fl = (float)limit;
    float valid = (coord >= -1.0f && coord <= fl) ? 1.0f : 0.0f;
    float c = fmaxf(coord, 0.0f);
    int low0 = (int)floorf(c);
    bool cap = low0 >= limit - 1;
    lo = cap ? limit - 1 : low0;
    hi = cap ? limit - 1 : low0 + 1;
    c = cap ? (float)lo : c;
    float l = c - (float)lo;
    w1 = l * valid;
    w0 = (1.0f - l) * valid;
}

__global__ void __launch_bounds__(256)
roi_align_fallback(const float* __restrict__ x, const float* __restrict__ rois,
                   float* __restrict__ out, int total) {
    int idx = blockIdx.x * blockDim.x + threadIdx.x;
    if (idx >= total) return;
    int pw = idx % PW;
    int ph = (idx / PW) % PH;
    int c  = (idx / (PW * PH)) % C_;
    int k  = idx / (PW * PH * C_);
    const float* r = rois + (size_t)k * 5;
    int b = (int)r[0];
    float start_w = r[1] * SCALE - 0.5f;
    float start_h = r[2] * SCALE - 0.5f;
    float bin_w = (r[3] * SCALE - 0.5f - start_w) / (float)PW;
    float bin_h = (r[4] * SCALE - 0.5f - start_h) / (float)PH;
    const float* xp = x + ((size_t)b * C_ + c) * (size_t)HW_;
    float acc = 0.0f;
#pragma unroll
    for (int sy = 0; sy < 2; ++sy) {
        float yc = start_h + ((float)ph + (sy + 0.5f) * 0.5f) * bin_h;
        int yl, yh; float wy0, wy1;
        axis_sample(yc, H_, yl, yh, wy0, wy1);
        const float* row0 = xp + (size_t)yl * W_;
        const float* row1 = xp + (size_t)yh * W_;
#pragma unroll
        for (int sx = 0; sx < 2; ++sx) {
            float xc = start_w + ((float)pw + (sx + 0.5f) * 0.5f) * bin_w;
            int xl, xh; float wx0, wx1;
            axis_sample(xc, W_, xl, xh, wx0, wx1);
            acc += wy0 * (wx0 * row0[xl] + wx1 * row0[xh])
                 + wy1 * (wx0 * row1[xl] + wx1 * row1[xh]);
        }
    }
    out[idx] = acc * 0.25f;
}

extern "C" void kernel_launch(void* const* d_in, const int* in_sizes, int n_in,
                              void* d_out, int out_size, void* d_ws, size_t ws_size,
                              hipStream_t stream) {
    const float* x    = (const float*)d_in[0];
    const float* rois = (const float*)d_in[1];
    float* out = (float*)d_out;
    int K = in_sizes[1] / 5;

    size_t need = (size_t)2 * HW_ * C_ * sizeof(__hip_bfloat16);  // 41 MB
    if (ws_size >= need) {
        __hip_bfloat16* xt = (__hip_bfloat16*)d_ws;
        dim3 tgrid(HW_ / 64, C_ / 64, 2);
        dim3 tblock(64, 8);
        transpose_kernel<<<tgrid, tblock, 0, stream>>>(x, xt);
        roi_main<<<K, 256, 0, stream>>>(xt, rois, out, K);
    } else {
        int total = K * C_ * PH * PW;
        roi_align_fallback<<<(total + 255) / 256, 256, 0, stream>>>(x, rois, out, total);
    }
}

// Round 3
// 67.944 us; speedup vs baseline: 2.7843x; 1.5846x over previous
//
#include <hip/hip_runtime.h>
#include <hip/hip_bf16.h>

// RoIAlign forward, aligned=True, sampling_ratio=2, pooled 7x7, scale 0.25.
// (1) transpose x [B,C,H,W] f32 -> xt [B,H*W,C] bf16 (channels-last).
// (2) one block (512 thr) per ROI: per-ROI bilinear tables in LDS, each
//     thread owns 8 consecutive channels (16B uint4 gathers, coalesced),
//     results staged in a 50KB LDS tile, then one contiguous float4 write
//     of the whole [C,7,7] output block (kills the 3x write amplification
//     + RMW fetch seen in round 2).

#define PH 7
#define PW 7
#define SCALE 0.25f
#define C_ 256
#define H_ 200
#define W_ 200
#define HW_ (H_ * W_)

// ---------------- transpose: x [B,C,HW] f32 -> xt [B,HW,C] bf16 --------------
__global__ void __launch_bounds__(512)
transpose_kernel(const float* __restrict__ x, __hip_bfloat16* __restrict__ xt) {
    __shared__ float tile[64][65];
    int hw0 = blockIdx.x * 64;
    int c0  = blockIdx.y * 64;
    int b   = blockIdx.z;
    int tx = threadIdx.x;   // 0..63
    int ty = threadIdx.y;   // 0..7
    const float* xb = x + (size_t)b * C_ * HW_;
#pragma unroll
    for (int j = 0; j < 8; ++j) {
        int cl = ty + 8 * j;
        tile[cl][tx] = xb[(size_t)(c0 + cl) * HW_ + hw0 + tx];
    }
    __syncthreads();
    __hip_bfloat16* xtb = xt + (size_t)b * HW_ * C_;
#pragma unroll
    for (int j = 0; j < 8; ++j) {
        int rl = ty + 8 * j;   // hw-local
        float v = tile[tx][rl];
        xtb[(size_t)(hw0 + rl) * C_ + c0 + tx] = __float2bfloat16(v);
    }
}

// ---------------- main: one block (512 thr) per ROI --------------------------
__global__ void __launch_bounds__(512)
roi_main(const __hip_bfloat16* __restrict__ xt, const float* __restrict__ rois,
         float* __restrict__ out, int K) {
    __shared__ float s_out[C_ * 49];          // 50176 B
    __shared__ int   s_ylo[14], s_yhi[14], s_xlo[14], s_xhi[14];
    __shared__ float s_wy0[14], s_wy1[14], s_wx0[14], s_wx1[14];
    __shared__ int   s_b;

    int k = blockIdx.x;
    int t = threadIdx.x;
    const float* r = rois + (size_t)k * 5;
    if (t == 0) s_b = (int)r[0];
    if (t < 28) {
        bool isy = t < 14;
        int i = isy ? t : t - 14;
        float start = (isy ? r[2] : r[1]) * SCALE - 0.5f;
        float end   = (isy ? r[4] : r[3]) * SCALE - 0.5f;
        float bin = (end - start) * (1.0f / 7.0f);
        int limit = isy ? H_ : W_;
        float pp   = (float)(i >> 1);
        float soff = (i & 1) ? 0.75f : 0.25f;
        float coord = fmaf(pp + soff, bin, start);
        float valid = (coord >= -1.0f && coord <= (float)limit) ? 1.0f : 0.0f;
        float cc = fmaxf(coord, 0.0f);
        int low0 = (int)floorf(cc);
        bool cap = low0 >= limit - 1;
        int lo = cap ? limit - 1 : low0;
        int hi = cap ? limit - 1 : low0 + 1;
        cc = cap ? (float)lo : cc;
        float l = cc - (float)lo;
        float w1 = l * valid, w0 = (1.0f - l) * valid;
        if (isy) { s_ylo[i] = lo; s_yhi[i] = hi; s_wy0[i] = w0; s_wy1[i] = w1; }
        else     { s_xlo[i] = lo; s_xhi[i] = hi; s_wx0[i] = w0; s_wx1[i] = w1; }
    }
    __syncthreads();

    int cg = t & 31;     // channel group: channels 8*cg .. 8*cg+7
    int pq = t >> 5;     // 0..15 -> handles p = pq, pq+16, pq+32, (pq+48)

    const __hip_bfloat16* xb = xt + (size_t)s_b * HW_ * C_ + cg * 8;

    for (int p = pq; p < 49; p += 16) {
        int ph = p / 7;
        int pw = p - ph * 7;
        float acc[8];
#pragma unroll
        for (int j = 0; j < 8; ++j) acc[j] = 0.0f;

#pragma unroll
        for (int sy = 0; sy < 2; ++sy) {
            int ys = 2 * ph + sy;
            int yl = s_ylo[ys], yh = s_yhi[ys];
            float wy0 = s_wy0[ys], wy1 = s_wy1[ys];
#pragma unroll
            for (int sx = 0; sx < 2; ++sx) {
                int xs = 2 * pw + sx;
                int xl = s_xlo[xs], xh = s_xhi[xs];
                float wx0 = s_wx0[xs], wx1 = s_wx1[xs];
                float w00 = wy0 * wx0, w01 = wy0 * wx1;
                float w10 = wy1 * wx0, w11 = wy1 * wx1;
                uint4 v00 = *(const uint4*)(xb + ((size_t)(yl * W_ + xl) << 8));
                uint4 v01 = *(const uint4*)(xb + ((size_t)(yl * W_ + xh) << 8));
                uint4 v10 = *(const uint4*)(xb + ((size_t)(yh * W_ + xl) << 8));
                uint4 v11 = *(const uint4*)(xb + ((size_t)(yh * W_ + xh) << 8));
                const unsigned* a00 = (const unsigned*)&v00;
                const unsigned* a01 = (const unsigned*)&v01;
                const unsigned* a10 = (const unsigned*)&v10;
                const unsigned* a11 = (const unsigned*)&v11;
#pragma unroll
                for (int w = 0; w < 4; ++w) {
                    float f00l = __uint_as_float(a00[w] << 16);
                    float f00h = __uint_as_float(a00[w] & 0xffff0000u);
                    float f01l = __uint_as_float(a01[w] << 16);
                    float f01h = __uint_as_float(a01[w] & 0xffff0000u);
                    float f10l = __uint_as_float(a10[w] << 16);
                    float f10h = __uint_as_float(a10[w] & 0xffff0000u);
                    float f11l = __uint_as_float(a11[w] << 16);
                    float f11h = __uint_as_float(a11[w] & 0xffff0000u);
                    acc[2 * w]     = fmaf(w00, f00l, acc[2 * w]);
                    acc[2 * w]     = fmaf(w01, f01l, acc[2 * w]);
                    acc[2 * w]     = fmaf(w10, f10l, acc[2 * w]);
                    acc[2 * w]     = fmaf(w11, f11l, acc[2 * w]);
                    acc[2 * w + 1] = fmaf(w00, f00h, acc[2 * w + 1]);
                    acc[2 * w + 1] = fmaf(w01, f01h, acc[2 * w + 1]);
                    acc[2 * w + 1] = fmaf(w10, f10h, acc[2 * w + 1]);
                    acc[2 * w + 1] = fmaf(w11, f11h, acc[2 * w + 1]);
                }
            }
        }
#pragma unroll
        for (int j = 0; j < 8; ++j)
            s_out[(cg * 8 + j) * 49 + p] = acc[j] * 0.25f;
    }
    __syncthreads();

    // cooperative contiguous write: 50176 B = 3136 float4
    const float4* sv = (const float4*)s_out;
    float4* ov = (float4*)(out + (size_t)k * C_ * 49);
    for (int i = t; i < (C_ * 49) / 4; i += 512)
        ov[i] = sv[i];
}

// ---------------- fallback (round-1 kernel) if ws too small ------------------
__device__ __forceinline__ void axis_sample(float coord, int limit,
                                            int& lo, int& hi,
                                            float& w0, float& w1) {
    float fl = (float)limit;
    float valid = (coord >= -1.0f && coord <= fl) ? 1.0f : 0.0f;
    float c = fmaxf(coord, 0.0f);
    int low0 = (int)floorf(c);
    bool cap = low0 >= limit - 1;
    lo = cap ? limit - 1 : low0;
    hi = cap ? limit - 1 : low0 + 1;
    c = cap ? (float)lo : c;
    float l = c - (float)lo;
    w1 = l * valid;
    w0 = (1.0f - l) * valid;
}

__global__ void __launch_bounds__(256)
roi_align_fallback(const float* __restrict__ x, const float* __restrict__ rois,
                   float* __restrict__ out, int total) {
    int idx = blockIdx.x * blockDim.x + threadIdx.x;
    if (idx >= total) return;
    int pw = idx % PW;
    int ph = (idx / PW) % PH;
    int c  = (idx / (PW * PH)) % C_;
    int k  = idx / (PW * PH * C_);
    const float* r = rois + (size_t)k * 5;
    int b = (int)r[0];
    float start_w = r[1] * SCALE - 0.5f;
    float start_h = r[2] * SCALE - 0.5f;
    float bin_w = (r[3] * SCALE - 0.5f - start_w) / (float)PW;
    float bin_h = (r[4] * SCALE - 0.5f - start_h) / (float)PH;
    const float* xp = x + ((size_t)b * C_ + c) * (size_t)HW_;
    float acc = 0.0f;
#pragma unroll
    for (int sy = 0; sy < 2; ++sy) {
        float yc = start_h + ((float)ph + (sy + 0.5f) * 0.5f) * bin_h;
        int yl, yh; float wy0, wy1;
        axis_sample(yc, H_, yl, yh, wy0, wy1);
        const float* row0 = xp + (size_t)yl * W_;
        const float* row1 = xp + (size_t)yh * W_;
#pragma unroll
        for (int sx = 0; sx < 2; ++sx) {
            float xc = start_w + ((float)pw + (sx + 0.5f) * 0.5f) * bin_w;
            int xl, xh; float wx0, wx1;
            axis_sample(xc, W_, xl, xh, wx0, wx1);
            acc += wy0 * (wx0 * row0[xl] + wx1 * row0[xh])
                 + wy1 * (wx0 * row1[xl] + wx1 * row1[xh]);
        }
    }
    out[idx] = acc * 0.25f;
}

extern "C" void kernel_launch(void* const* d_in, const int* in_sizes, int n_in,
                              void* d_out, int out_size, void* d_ws, size_t ws_size,
                              hipStream_t stream) {
    const float* x    = (const float*)d_in[0];
    const float* rois = (const float*)d_in[1];
    float* out = (float*)d_out;
    int K = in_sizes[1] / 5;

    size_t need = (size_t)2 * HW_ * C_ * sizeof(__hip_bfloat16);  // 41 MB
    if (ws_size >= need) {
        __hip_bfloat16* xt = (__hip_bfloat16*)d_ws;
        dim3 tgrid(HW_ / 64, C_ / 64, 2);
        dim3 tblock(64, 8);
        transpose_kernel<<<tgrid, tblock, 0, stream>>>(x, xt);
        roi_main<<<K, 512, 0, stream>>>(xt, rois, out, K);
    } else {
        int total = K * C_ * PH * PW;
        roi_align_fallback<<<(total + 255) / 256, 256, 0, stream>>>(x, rois, out, total);
    }
}

// Round 5
// 62.700 us; speedup vs baseline: 3.0172x; 1.0836x over previous
//
#include <hip/hip_runtime.h>
#include <hip/hip_bf16.h>

// RoIAlign forward, aligned=True, sampling_ratio=2, pooled 7x7, scale 0.25.
// (1) transpose x [B,C,H,W] f32 -> xt [B,H*W,C] bf16 (channels-last).
// (2) two blocks (512 thr) per ROI, one per 128-channel half: per-ROI bilinear
//     tables in LDS, each thread owns 8 consecutive channels (16B uint4
//     gathers), results staged in 25KB LDS, one contiguous float4 write.

#define PH 7
#define PW 7
#define SCALE 0.25f
#define C_ 256
#define CH_ 128              // channels per block (half)
#define H_ 200
#define W_ 200
#define HW_ (H_ * W_)

typedef float f32x4 __attribute__((ext_vector_type(4)));

// ---------------- transpose: x [B,C,HW] f32 -> xt [B,HW,C] bf16 --------------
__global__ void __launch_bounds__(512)
transpose_kernel(const float* __restrict__ x, __hip_bfloat16* __restrict__ xt) {
    __shared__ float tile[64][65];
    int hw0 = blockIdx.x * 64;
    int c0  = blockIdx.y * 64;
    int b   = blockIdx.z;
    int tx = threadIdx.x;   // 0..63
    int ty = threadIdx.y;   // 0..7
    const float* xb = x + (size_t)b * C_ * HW_;
#pragma unroll
    for (int j = 0; j < 8; ++j) {
        int cl = ty + 8 * j;
        tile[cl][tx] = __builtin_nontemporal_load(&xb[(size_t)(c0 + cl) * HW_ + hw0 + tx]);
    }
    __syncthreads();
    __hip_bfloat16* xtb = xt + (size_t)b * HW_ * C_;
#pragma unroll
    for (int j = 0; j < 8; ++j) {
        int rl = ty + 8 * j;   // hw-local
        float v = tile[tx][rl];
        xtb[(size_t)(hw0 + rl) * C_ + c0 + tx] = __float2bfloat16(v);
    }
}

// ---------------- main: 2 blocks (512 thr) per ROI ---------------------------
__global__ void __launch_bounds__(512)
roi_main(const __hip_bfloat16* __restrict__ xt, const float* __restrict__ rois,
         float* __restrict__ out, int K) {
    __shared__ float s_out[CH_ * 49];         // 25088 B
    __shared__ int   s_ylo[14], s_yhi[14], s_xlo[14], s_xhi[14];
    __shared__ float s_wy0[14], s_wy1[14], s_wx0[14], s_wx1[14];
    __shared__ int   s_b;

    int k     = blockIdx.x >> 1;
    int chalf = blockIdx.x & 1;
    int t = threadIdx.x;
    const float* r = rois + (size_t)k * 5;
    if (t == 0) s_b = (int)r[0];
    if (t < 28) {
        bool isy = t < 14;
        int i = isy ? t : t - 14;
        float start = (isy ? r[2] : r[1]) * SCALE - 0.5f;
        float end   = (isy ? r[4] : r[3]) * SCALE - 0.5f;
        float bin = (end - start) * (1.0f / 7.0f);
        int limit = isy ? H_ : W_;
        float pp   = (float)(i >> 1);
        float soff = (i & 1) ? 0.75f : 0.25f;
        float coord = fmaf(pp + soff, bin, start);
        float valid = (coord >= -1.0f && coord <= (float)limit) ? 1.0f : 0.0f;
        float cc = fmaxf(coord, 0.0f);
        int low0 = (int)floorf(cc);
        bool cap = low0 >= limit - 1;
        int lo = cap ? limit - 1 : low0;
        int hi = cap ? limit - 1 : low0 + 1;
        cc = cap ? (float)lo : cc;
        float l = cc - (float)lo;
        float w1 = l * valid, w0 = (1.0f - l) * valid;
        if (isy) { s_ylo[i] = lo; s_yhi[i] = hi; s_wy0[i] = w0; s_wy1[i] = w1; }
        else     { s_xlo[i] = lo; s_xhi[i] = hi; s_wx0[i] = w0; s_wx1[i] = w1; }
    }
    __syncthreads();

    int cg = t & 15;     // channel group within half: channels 8*cg .. 8*cg+7
    int pq = t >> 4;     // 0..31 -> handles p = pq, pq+32

    const __hip_bfloat16* xb = xt + (size_t)s_b * HW_ * C_ + chalf * CH_ + cg * 8;

    for (int p = pq; p < 49; p += 32) {
        int ph = p / 7;
        int pw = p - ph * 7;
        float acc[8];
#pragma unroll
        for (int j = 0; j < 8; ++j) acc[j] = 0.0f;

#pragma unroll
        for (int sy = 0; sy < 2; ++sy) {
            int ys = 2 * ph + sy;
            int yl = s_ylo[ys], yh = s_yhi[ys];
            float wy0 = s_wy0[ys], wy1 = s_wy1[ys];
#pragma unroll
            for (int sx = 0; sx < 2; ++sx) {
                int xs = 2 * pw + sx;
                int xl = s_xlo[xs], xh = s_xhi[xs];
                float wx0 = s_wx0[xs], wx1 = s_wx1[xs];
                float w00 = wy0 * wx0, w01 = wy0 * wx1;
                float w10 = wy1 * wx0, w11 = wy1 * wx1;
                uint4 v00 = *(const uint4*)(xb + ((size_t)(yl * W_ + xl) << 8));
                uint4 v01 = *(const uint4*)(xb + ((size_t)(yl * W_ + xh) << 8));
                uint4 v10 = *(const uint4*)(xb + ((size_t)(yh * W_ + xl) << 8));
                uint4 v11 = *(const uint4*)(xb + ((size_t)(yh * W_ + xh) << 8));
                const unsigned* a00 = (const unsigned*)&v00;
                const unsigned* a01 = (const unsigned*)&v01;
                const unsigned* a10 = (const unsigned*)&v10;
                const unsigned* a11 = (const unsigned*)&v11;
#pragma unroll
                for (int w = 0; w < 4; ++w) {
                    float f00l = __uint_as_float(a00[w] << 16);
                    float f00h = __uint_as_float(a00[w] & 0xffff0000u);
                    float f01l = __uint_as_float(a01[w] << 16);
                    float f01h = __uint_as_float(a01[w] & 0xffff0000u);
                    float f10l = __uint_as_float(a10[w] << 16);
                    float f10h = __uint_as_float(a10[w] & 0xffff0000u);
                    float f11l = __uint_as_float(a11[w] << 16);
                    float f11h = __uint_as_float(a11[w] & 0xffff0000u);
                    acc[2 * w]     = fmaf(w00, f00l, acc[2 * w]);
                    acc[2 * w]     = fmaf(w01, f01l, acc[2 * w]);
                    acc[2 * w]     = fmaf(w10, f10l, acc[2 * w]);
                    acc[2 * w]     = fmaf(w11, f11l, acc[2 * w]);
                    acc[2 * w + 1] = fmaf(w00, f00h, acc[2 * w + 1]);
                    acc[2 * w + 1] = fmaf(w01, f01h, acc[2 * w + 1]);
                    acc[2 * w + 1] = fmaf(w10, f10h, acc[2 * w + 1]);
                    acc[2 * w + 1] = fmaf(w11, f11h, acc[2 * w + 1]);
                }
            }
        }
#pragma unroll
        for (int j = 0; j < 8; ++j)
            s_out[(cg * 8 + j) * 49 + p] = acc[j] * 0.25f;
    }
    __syncthreads();

    // cooperative contiguous write: 25088 B = 1568 float4
    const f32x4* sv = (const f32x4*)s_out;
    f32x4* ov = (f32x4*)(out + ((size_t)k * C_ + chalf * CH_) * 49);
    for (int i = t; i < (CH_ * 49) / 4; i += 512)
        __builtin_nontemporal_store(sv[i], &ov[i]);
}

// ---------------- fallback (round-1 kernel) if ws too small ------------------
__device__ __forceinline__ void axis_sample(float coord, int limit,
                                            int& lo, int& hi,
                                            float& w0, float& w1) {
    float fl = (float)limit;
    float valid = (coord >= -1.0f && coord <= fl) ? 1.0f : 0.0f;
    float c = fmaxf(coord, 0.0f);
    int low0 = (int)floorf(c);
    bool cap = low0 >= limit - 1;
    lo = cap ? limit - 1 : low0;
    hi = cap ? limit - 1 : low0 + 1;
    c = cap ? (float)lo : c;
    float l = c - (float)lo;
    w1 = l * valid;
    w0 = (1.0f - l) * valid;
}

__global__ void __launch_bounds__(256)
roi_align_fallback(const float* __restrict__ x, const float* __restrict__ rois,
                   float* __restrict__ out, int total) {
    int idx = blockIdx.x * blockDim.x + threadIdx.x;
    if (idx >= total) return;
    int pw = idx % PW;
    int ph = (idx / PW) % PH;
    int c  = (idx / (PW * PH)) % C_;
    int k  = idx / (PW * PH * C_);
    const float* r = rois + (size_t)k * 5;
    int b = (int)r[0];
    float start_w = r[1] * SCALE - 0.5f;
    float start_h = r[2] * SCALE - 0.5f;
    float bin_w = (r[3] * SCALE - 0.5f - start_w) / (float)PW;
    float bin_h = (r[4] * SCALE - 0.5f - start_h) / (float)PH;
    const float* xp = x + ((size_t)b * C_ + c) * (size_t)HW_;
    float acc = 0.0f;
#pragma unroll
    for (int sy = 0; sy < 2; ++sy) {
        float yc = start_h + ((float)ph + (sy + 0.5f) * 0.5f) * bin_h;
        int yl, yh; float wy0, wy1;
        axis_sample(yc, H_, yl, yh, wy0, wy1);
        const float* row0 = xp + (size_t)yl * W_;
        const float* row1 = xp + (size_t)yh * W_;
#pragma unroll
        for (int sx = 0; sx < 2; ++sx) {
            float xc = start_w + ((float)pw + (sx + 0.5f) * 0.5f) * bin_w;
            int xl, xh; float wx0, wx1;
            axis_sample(xc, W_, xl, xh, wx0, wx1);
            acc += wy0 * (wx0 * row0[xl] + wx1 * row0[xh])
                 + wy1 * (wx0 * row1[xl] + wx1 * row1[xh]);
        }
    }
    out[idx] = acc * 0.25f;
}

extern "C" void kernel_launch(void* const* d_in, const int* in_sizes, int n_in,
                              void* d_out, int out_size, void* d_ws, size_t ws_size,
                              hipStream_t stream) {
    const float* x    = (const float*)d_in[0];
    const float* rois = (const float*)d_in[1];
    float* out = (float*)d_out;
    int K = in_sizes[1] / 5;

    size_t need = (size_t)2 * HW_ * C_ * sizeof(__hip_bfloat16);  // 41 MB
    if (ws_size >= need) {
        __hip_bfloat16* xt = (__hip_bfloat16*)d_ws;
        dim3 tgrid(HW_ / 64, C_ / 64, 2);
        dim3 tblock(64, 8);
        transpose_kernel<<<tgrid, tblock, 0, stream>>>(x, xt);
        roi_main<<<K * 2, 512, 0, stream>>>(xt, rois, out, K);
    } else {
        int total = K * C_ * PH * PW;
        roi_align_fallback<<<(total + 255) / 256, 256, 0, stream>>>(x, rois, out, total);
    }
}

// Round 6
// 59.970 us; speedup vs baseline: 3.1545x; 1.0455x over previous
//
#include <hip/hip_runtime.h>
#include <hip/hip_bf16.h>

// RoIAlign forward, aligned=True, sampling_ratio=2, pooled 7x7, scale 0.25.
// (1) transpose x [B,C,H,W] f32 -> xt [B,H*W,C] bf16 (channels-last).
// (1b) sort ROIs by (batch, y-center) on device (bitonic, 1 block).
// (2) two blocks (512 thr) per ROI (one per 128-channel half), dispatched via
//     a bijective XCD-chunked swizzle over the *sorted* ROI order so blocks
//     co-resident on one XCD share an xt y-band that fits its 4 MiB L2
//     (gathers were L3-bound: ~400 MB logical corner traffic, random ROI
//     order thrashed L2). Per-ROI bilinear tables in LDS, 16B uint4 gathers,
//     25KB LDS output stage, contiguous nontemporal float4 write.

#define PH 7
#define PW 7
#define SCALE 0.25f
#define C_ 256
#define CH_ 128              // channels per block (half)
#define H_ 200
#define W_ 200
#define HW_ (H_ * W_)

typedef float f32x4 __attribute__((ext_vector_type(4)));

// ---------------- transpose: x [B,C,HW] f32 -> xt [B,HW,C] bf16 --------------
__global__ void __launch_bounds__(512)
transpose_kernel(const float* __restrict__ x, __hip_bfloat16* __restrict__ xt) {
    __shared__ float tile[64][65];
    int hw0 = blockIdx.x * 64;
    int c0  = blockIdx.y * 64;
    int b   = blockIdx.z;
    int tx = threadIdx.x;   // 0..63
    int ty = threadIdx.y;   // 0..7
    const float* xb = x + (size_t)b * C_ * HW_;
#pragma unroll
    for (int j = 0; j < 8; ++j) {
        int cl = ty + 8 * j;
        tile[cl][tx] = __builtin_nontemporal_load(&xb[(size_t)(c0 + cl) * HW_ + hw0 + tx]);
    }
    __syncthreads();
    __hip_bfloat16* xtb = xt + (size_t)b * HW_ * C_;
#pragma unroll
    for (int j = 0; j < 8; ++j) {
        int rl = ty + 8 * j;   // hw-local
        float v = tile[tx][rl];
        xtb[(size_t)(hw0 + rl) * C_ + c0 + tx] = __float2bfloat16(v);
    }
}

// ---------------- ROI sort by (batch, y-center): bitonic over 1024 -----------
__global__ void __launch_bounds__(1024)
sort_rois_kernel(const float* __restrict__ rois, int K, int* __restrict__ perm) {
    __shared__ int s[1024];
    int t = threadIdx.x;
    int key;
    if (t < K) {
        const float* r = rois + (size_t)t * 5;
        int b = (int)r[0];
        float yc = (r[2] + r[4]) * (0.5f * SCALE);   // feature-space y center
        int yq = min(max((int)yc, 0), 511);
        key = ((b * 512 + yq) << 12) | t;            // low bits: index (unique)
    } else {
        key = 0x7FFFFFFF;
    }
    s[t] = key;
    __syncthreads();
    for (int k2 = 2; k2 <= 1024; k2 <<= 1) {
        for (int j = k2 >> 1; j > 0; j >>= 1) {
            int ixj = t ^ j;
            if (ixj > t) {
                int a = s[t], bv = s[ixj];
                bool up = ((t & k2) == 0);
                if ((a > bv) == up) { s[t] = bv; s[ixj] = a; }
            }
            __syncthreads();
        }
    }
    if (t < K) perm[t] = s[t] & 0xFFF;
}

__global__ void identity_perm_kernel(int K, int* __restrict__ perm) {
    int i = blockIdx.x * blockDim.x + threadIdx.x;
    if (i < K) perm[i] = i;
}

// ---------------- main: 2 blocks (512 thr) per ROI ---------------------------
__global__ void __launch_bounds__(512)
roi_main(const __hip_bfloat16* __restrict__ xt, const float* __restrict__ rois,
         const int* __restrict__ perm, float* __restrict__ out, int K) {
    __shared__ float s_out[CH_ * 49];         // 25088 B
    __shared__ int   s_ylo[14], s_yhi[14], s_xlo[14], s_xhi[14];
    __shared__ float s_wy0[14], s_wy1[14], s_wx0[14], s_wx1[14];
    __shared__ int   s_b;

    // bijective XCD-chunked swizzle (m204): each XCD gets a contiguous run of
    // the sorted ROI order -> co-resident blocks share an xt y-band in its L2.
    int nwg = gridDim.x;
    int q = nwg >> 3, rr = nwg & 7;
    int xcd = blockIdx.x & 7, pos = blockIdx.x >> 3;
    int logical = (xcd < rr ? xcd * (q + 1) : rr * (q + 1) + (xcd - rr) * q) + pos;

    int k     = perm[logical >> 1];
    int chalf = logical & 1;
    int t = threadIdx.x;
    const float* r = rois + (size_t)k * 5;
    if (t == 0) s_b = (int)r[0];
    if (t < 28) {
        bool isy = t < 14;
        int i = isy ? t : t - 14;
        float start = (isy ? r[2] : r[1]) * SCALE - 0.5f;
        float end   = (isy ? r[4] : r[3]) * SCALE - 0.5f;
        float bin = (end - start) * (1.0f / 7.0f);
        int limit = isy ? H_ : W_;
        float pp   = (float)(i >> 1);
        float soff = (i & 1) ? 0.75f : 0.25f;
        float coord = fmaf(pp + soff, bin, start);
        float valid = (coord >= -1.0f && coord <= (float)limit) ? 1.0f : 0.0f;
        float cc = fmaxf(coord, 0.0f);
        int low0 = (int)floorf(cc);
        bool cap = low0 >= limit - 1;
        int lo = cap ? limit - 1 : low0;
        int hi = cap ? limit - 1 : low0 + 1;
        cc = cap ? (float)lo : cc;
        float l = cc - (float)lo;
        float w1 = l * valid, w0 = (1.0f - l) * valid;
        if (isy) { s_ylo[i] = lo; s_yhi[i] = hi; s_wy0[i] = w0; s_wy1[i] = w1; }
        else     { s_xlo[i] = lo; s_xhi[i] = hi; s_wx0[i] = w0; s_wx1[i] = w1; }
    }
    __syncthreads();

    int cg = t & 15;     // channel group within half: channels 8*cg .. 8*cg+7
    int pq = t >> 4;     // 0..31 -> handles p = pq, pq+32

    const __hip_bfloat16* xb = xt + (size_t)s_b * HW_ * C_ + chalf * CH_ + cg * 8;

    for (int p = pq; p < 49; p += 32) {
        int ph = p / 7;
        int pw = p - ph * 7;
        float acc[8];
#pragma unroll
        for (int j = 0; j < 8; ++j) acc[j] = 0.0f;

#pragma unroll
        for (int sy = 0; sy < 2; ++sy) {
            int ys = 2 * ph + sy;
            int yl = s_ylo[ys], yh = s_yhi[ys];
            float wy0 = s_wy0[ys], wy1 = s_wy1[ys];
#pragma unroll
            for (int sx = 0; sx < 2; ++sx) {
                int xs = 2 * pw + sx;
                int xl = s_xlo[xs], xh = s_xhi[xs];
                float wx0 = s_wx0[xs], wx1 = s_wx1[xs];
                float w00 = wy0 * wx0, w01 = wy0 * wx1;
                float w10 = wy1 * wx0, w11 = wy1 * wx1;
                uint4 v00 = *(const uint4*)(xb + ((size_t)(yl * W_ + xl) << 8));
                uint4 v01 = *(const uint4*)(xb + ((size_t)(yl * W_ + xh) << 8));
                uint4 v10 = *(const uint4*)(xb + ((size_t)(yh * W_ + xl) << 8));
                uint4 v11 = *(const uint4*)(xb + ((size_t)(yh * W_ + xh) << 8));
                const unsigned* a00 = (const unsigned*)&v00;
                const unsigned* a01 = (const unsigned*)&v01;
                const unsigned* a10 = (const unsigned*)&v10;
                const unsigned* a11 = (const unsigned*)&v11;
#pragma unroll
                for (int w = 0; w < 4; ++w) {
                    float f00l = __uint_as_float(a00[w] << 16);
                    float f00h = __uint_as_float(a00[w] & 0xffff0000u);
                    float f01l = __uint_as_float(a01[w] << 16);
                    float f01h = __uint_as_float(a01[w] & 0xffff0000u);
                    float f10l = __uint_as_float(a10[w] << 16);
                    float f10h = __uint_as_float(a10[w] & 0xffff0000u);
                    float f11l = __uint_as_float(a11[w] << 16);
                    float f11h = __uint_as_float(a11[w] & 0xffff0000u);
                    acc[2 * w]     = fmaf(w00, f00l, acc[2 * w]);
                    acc[2 * w]     = fmaf(w01, f01l, acc[2 * w]);
                    acc[2 * w]     = fmaf(w10, f10l, acc[2 * w]);
                    acc[2 * w]     = fmaf(w11, f11l, acc[2 * w]);
                    acc[2 * w + 1] = fmaf(w00, f00h, acc[2 * w + 1]);
                    acc[2 * w + 1] = fmaf(w01, f01h, acc[2 * w + 1]);
                    acc[2 * w + 1] = fmaf(w10, f10h, acc[2 * w + 1]);
                    acc[2 * w + 1] = fmaf(w11, f11h, acc[2 * w + 1]);
                }
            }
        }
#pragma unroll
        for (int j = 0; j < 8; ++j)
            s_out[(cg * 8 + j) * 49 + p] = acc[j] * 0.25f;
    }
    __syncthreads();

    // cooperative contiguous write: 25088 B = 1568 float4
    const f32x4* sv = (const f32x4*)s_out;
    f32x4* ov = (f32x4*)(out + ((size_t)k * C_ + chalf * CH_) * 49);
    for (int i = t; i < (CH_ * 49) / 4; i += 512)
        __builtin_nontemporal_store(sv[i], &ov[i]);
}

// ---------------- fallback (round-1 kernel) if ws too small ------------------
__device__ __forceinline__ void axis_sample(float coord, int limit,
                                            int& lo, int& hi,
                                            float& w0, float& w1) {
    float fl = (float)limit;
    float valid = (coord >= -1.0f && coord <= fl) ? 1.0f : 0.0f;
    float c = fmaxf(coord, 0.0f);
    int low0 = (int)floorf(c);
    bool cap = low0 >= limit - 1;
    lo = cap ? limit - 1 : low0;
    hi = cap ? limit - 1 : low0 + 1;
    c = cap ? (float)lo : c;
    float l = c - (float)lo;
    w1 = l * valid;
    w0 = (1.0f - l) * valid;
}

__global__ void __launch_bounds__(256)
roi_align_fallback(const float* __restrict__ x, const float* __restrict__ rois,
                   float* __restrict__ out, int total) {
    int idx = blockIdx.x * blockDim.x + threadIdx.x;
    if (idx >= total) return;
    int pw = idx % PW;
    int ph = (idx / PW) % PH;
    int c  = (idx / (PW * PH)) % C_;
    int k  = idx / (PW * PH * C_);
    const float* r = rois + (size_t)k * 5;
    int b = (int)r[0];
    float start_w = r[1] * SCALE - 0.5f;
    float start_h = r[2] * SCALE - 0.5f;
    float bin_w = (r[3] * SCALE - 0.5f - start_w) / (float)PW;
    float bin_h = (r[4] * SCALE - 0.5f - start_h) / (float)PH;
    const float* xp = x + ((size_t)b * C_ + c) * (size_t)HW_;
    float acc = 0.0f;
#pragma unroll
    for (int sy = 0; sy < 2; ++sy) {
        float yc = start_h + ((float)ph + (sy + 0.5f) * 0.5f) * bin_h;
        int yl, yh; float wy0, wy1;
        axis_sample(yc, H_, yl, yh, wy0, wy1);
        const float* row0 = xp + (size_t)yl * W_;
        const float* row1 = xp + (size_t)yh * W_;
#pragma unroll
        for (int sx = 0; sx < 2; ++sx) {
            float xc = start_w + ((float)pw + (sx + 0.5f) * 0.5f) * bin_w;
            int xl, xh; float wx0, wx1;
            axis_sample(xc, W_, xl, xh, wx0, wx1);
            acc += wy0 * (wx0 * row0[xl] + wx1 * row0[xh])
                 + wy1 * (wx0 * row1[xl] + wx1 * row1[xh]);
        }
    }
    out[idx] = acc * 0.25f;
}

extern "C" void kernel_launch(void* const* d_in, const int* in_sizes, int n_in,
                              void* d_out, int out_size, void* d_ws, size_t ws_size,
                              hipStream_t stream) {
    const float* x    = (const float*)d_in[0];
    const float* rois = (const float*)d_in[1];
    float* out = (float*)d_out;
    int K = in_sizes[1] / 5;

    size_t xtbytes = (size_t)2 * HW_ * C_ * sizeof(__hip_bfloat16);  // 40.96 MB
    size_t need = xtbytes + 4096 * sizeof(int);
    if (ws_size >= need && K <= 4096) {
        __hip_bfloat16* xt = (__hip_bfloat16*)d_ws;
        int* perm = (int*)((char*)d_ws + xtbytes);
        dim3 tgrid(HW_ / 64, C_ / 64, 2);
        dim3 tblock(64, 8);
        transpose_kernel<<<tgrid, tblock, 0, stream>>>(x, xt);
        if (K <= 1024)
            sort_rois_kernel<<<1, 1024, 0, stream>>>(rois, K, perm);
        else
            identity_perm_kernel<<<(K + 255) / 256, 256, 0, stream>>>(K, perm);
        roi_main<<<K * 2, 512, 0, stream>>>(xt, rois, perm, out, K);
    } else {
        int total = K * C_ * PH * PW;
        roi_align_fallback<<<(total + 255) / 256, 256, 0, stream>>>(x, rois, out, total);
    }
}

// Round 7
// 51.269 us; speedup vs baseline: 3.6899x; 1.1697x over previous
//
#include <hip/hip_runtime.h>
#include <hip/hip_bf16.h>

// RoIAlign forward, aligned=True, sampling_ratio=2, pooled 7x7, scale 0.25.
// (1) transpose x [B,C,H,W] f32 -> xt [B,H*W,C] bf16; one extra block in the
//     same kernel bitonic-sorts ROIs by (batch, y-center) -> perm (hidden
//     under the transpose, no serial sort kernel).
// (2) roi_main: 2 blocks per ROI (channel halves). Swizzle: chalf = XCD>=4,
//     sorted-ROI chunks per XCD&3 -> each XCD touches only 256B/row, halving
//     its L2 footprint. Lanes: cg=t&15 (8ch each), xc=bit4 (x-corner), so the
//     (yl,xl)+(yl,xh) corner pair is ONE contiguous 512B span per 32 lanes
//     (8 loads/bin instead of 16, 2x512B segments/instr instead of 4x256B).
//     x-corner partials combined via shfl_xor(16). 25KB LDS out stage,
//     contiguous nontemporal write.

#define PH 7
#define PW 7
#define SCALE 0.25f
#define C_ 256
#define CH_ 128
#define H_ 200
#define W_ 200
#define HW_ (H_ * W_)

typedef float f32x4 __attribute__((ext_vector_type(4)));

// -------- transpose + hidden ROI sort ---------------------------------------
__global__ void __launch_bounds__(512)
transpose_sort_kernel(const float* __restrict__ x, __hip_bfloat16* __restrict__ xt,
                      const float* __restrict__ rois, int K, int mode,
                      int* __restrict__ perm) {
    __shared__ float tile[64][65];
    __shared__ int s[1024];
    int bx = blockIdx.x;
    int tx = threadIdx.x;   // 0..63
    int ty = threadIdx.y;   // 0..7
    int t = ty * 64 + tx;   // 0..511

    if (bx == gridDim.x - 1) {
        // ---- sort block (one per grid; others with by/bz>0 exit) ----
        if (blockIdx.y != 0 || blockIdx.z != 0) return;
        if (mode == 1) {
            // bitonic sort of up to 1024 keys with 512 threads
            for (int i = t; i < 1024; i += 512) {
                int key;
                if (i < K) {
                    const float* r = rois + (size_t)i * 5;
                    int b = (int)r[0];
                    float yc = (r[2] + r[4]) * (0.5f * SCALE);
                    int yq = min(max((int)yc, 0), 511);
                    key = ((b * 512 + yq) << 12) | i;
                } else {
                    key = 0x7FFFFFFF;
                }
                s[i] = key;
            }
            __syncthreads();
            for (int k2 = 2; k2 <= 1024; k2 <<= 1) {
                for (int j = k2 >> 1; j > 0; j >>= 1) {
                    int i = ((t & ~(j - 1)) << 1) | (t & (j - 1));
                    int l = i | j;
                    int a = s[i], b = s[l];
                    bool up = ((i & k2) == 0);
                    if ((a > b) == up) { s[i] = b; s[l] = a; }
                    __syncthreads();
                }
            }
            for (int i = t; i < K; i += 512) perm[i] = s[i] & 0xFFF;
        } else {
            for (int i = t; i < K; i += 512) perm[i] = i;
        }
        return;
    }

    // ---- transpose block ----
    int hw0 = bx * 64;
    int c0  = blockIdx.y * 64;
    int b   = blockIdx.z;
    const float* xb = x + (size_t)b * C_ * HW_;
#pragma unroll
    for (int j = 0; j < 8; ++j) {
        int cl = ty + 8 * j;
        tile[cl][tx] = __builtin_nontemporal_load(&xb[(size_t)(c0 + cl) * HW_ + hw0 + tx]);
    }
    __syncthreads();
    __hip_bfloat16* xtb = xt + (size_t)b * HW_ * C_;
#pragma unroll
    for (int j = 0; j < 8; ++j) {
        int rl = ty + 8 * j;
        float v = tile[tx][rl];
        xtb[(size_t)(hw0 + rl) * C_ + c0 + tx] = __float2bfloat16(v);
    }
}

// -------- main: 2 blocks (512 thr) per ROI ----------------------------------
__global__ void __launch_bounds__(512)
roi_main(const __hip_bfloat16* __restrict__ xt, const float* __restrict__ rois,
         const int* __restrict__ perm, float* __restrict__ out, int K, int mode) {
    __shared__ float s_out[CH_ * 49];         // 25088 B
    __shared__ int   s_ylo[14], s_yhi[14], s_xlo[14];
    __shared__ float s_wy0[14], s_wy1[14], s_wx0[14], s_wx1[14];
    __shared__ int   s_b;

    int k, chalf;
    if (mode == 1) {
        // chalf = xcd>=4; ROI chunks over xcd&3 (K%4==0 guaranteed)
        int xcd  = blockIdx.x & 7;
        int pos  = blockIdx.x >> 3;
        chalf    = xcd >> 2;
        int rank = (xcd & 3) * (K >> 2) + pos;
        k = perm[rank];
    } else {
        int nwg = gridDim.x;
        int q = nwg >> 3, rr = nwg & 7;
        int xcd = blockIdx.x & 7, pos = blockIdx.x >> 3;
        int logical = (xcd < rr ? xcd * (q + 1) : rr * (q + 1) + (xcd - rr) * q) + pos;
        k = perm[logical >> 1];
        chalf = logical & 1;
    }

    int t = threadIdx.x;
    const float* r = rois + (size_t)k * 5;
    if (t == 0) s_b = (int)r[0];
    if (t < 28) {
        bool isy = t < 14;
        int i = isy ? t : t - 14;
        float start = (isy ? r[2] : r[1]) * SCALE - 0.5f;
        float end   = (isy ? r[4] : r[3]) * SCALE - 0.5f;
        float bin = (end - start) * (1.0f / 7.0f);
        int limit = isy ? H_ : W_;
        float pp   = (float)(i >> 1);
        float soff = (i & 1) ? 0.75f : 0.25f;
        float coord = fmaf(pp + soff, bin, start);
        float valid = (coord >= -1.0f && coord <= (float)limit) ? 1.0f : 0.0f;
        float cc = fmaxf(coord, 0.0f);
        int low0 = (int)floorf(cc);
        bool cap = low0 >= limit - 1;
        int lo = cap ? limit - 1 : low0;
        int hi = cap ? limit - 1 : low0 + 1;
        cc = cap ? (float)lo : cc;
        float l = cc - (float)lo;
        float w1 = l * valid, w0 = (1.0f - l) * valid;
        if (isy) {
            // fold the 1/4 sample average into the y weights
            s_ylo[i] = lo; s_yhi[i] = hi;
            s_wy0[i] = w0 * 0.25f; s_wy1[i] = w1 * 0.25f;
        } else {
            s_xlo[i] = lo;
            s_wx0[i] = w0; s_wx1[i] = w1;
        }
    }
    __syncthreads();

    int cg    = t & 15;        // channels 8*cg..8*cg+7 within the half
    int xc    = (t >> 4) & 1;  // which x-corner this lane accumulates
    int pslot = t >> 5;        // 0..15 -> p = pslot, pslot+16, pslot+32, ...

    const __hip_bfloat16* xb = xt + (size_t)s_b * HW_ * C_ + chalf * CH_ + cg * 8;

    for (int p = pslot; p < 49; p += 16) {
        int ph = p / 7;
        int pw = p - ph * 7;
        float acc[8];
#pragma unroll
        for (int j = 0; j < 8; ++j) acc[j] = 0.0f;

#pragma unroll
        for (int sy = 0; sy < 2; ++sy) {
            int ys = 2 * ph + sy;
            int yl = s_ylo[ys], yh = s_yhi[ys];
            float wy0 = s_wy0[ys], wy1 = s_wy1[ys];
#pragma unroll
            for (int sx = 0; sx < 2; ++sx) {
                int xs = 2 * pw + sx;
                int xi = s_xlo[xs] + xc;   // xc=1 reads xl+1 (=xh except cap; then weight=0)
                float wxm = xc ? s_wx1[xs] : s_wx0[xs];
                float wl = wy0 * wxm, wh = wy1 * wxm;
                uint4 vlo = *(const uint4*)(xb + ((size_t)(yl * W_ + xi) << 8));
                uint4 vhi = *(const uint4*)(xb + ((size_t)(yh * W_ + xi) << 8));
                const unsigned* alo = (const unsigned*)&vlo;
                const unsigned* ahi = (const unsigned*)&vhi;
#pragma unroll
                for (int w = 0; w < 4; ++w) {
                    float flo0 = __uint_as_float(alo[w] << 16);
                    float flo1 = __uint_as_float(alo[w] & 0xffff0000u);
                    float fhi0 = __uint_as_float(ahi[w] << 16);
                    float fhi1 = __uint_as_float(ahi[w] & 0xffff0000u);
                    acc[2 * w]     = fmaf(wl, flo0, acc[2 * w]);
                    acc[2 * w]     = fmaf(wh, fhi0, acc[2 * w]);
                    acc[2 * w + 1] = fmaf(wl, flo1, acc[2 * w + 1]);
                    acc[2 * w + 1] = fmaf(wh, fhi1, acc[2 * w + 1]);
                }
            }
        }
        // combine the two x-corner partials, store once
#pragma unroll
        for (int j = 0; j < 8; ++j) {
            float v = acc[j] + __shfl_xor(acc[j], 16, 64);
            if (xc == 0) s_out[(cg * 8 + j) * 49 + p] = v;
        }
    }
    __syncthreads();

    const f32x4* sv = (const f32x4*)s_out;
    f32x4* ov = (f32x4*)(out + ((size_t)k * C_ + chalf * CH_) * 49);
    for (int i = t; i < (CH_ * 49) / 4; i += 512)
        __builtin_nontemporal_store(sv[i], &ov[i]);
}

// -------- fallback (round-1 kernel) if ws too small -------------------------
__device__ __forceinline__ void axis_sample(float coord, int limit,
                                            int& lo, int& hi,
                                            float& w0, float& w1) {
    float fl = (float)limit;
    float valid = (coord >= -1.0f && coord <= fl) ? 1.0f : 0.0f;
    float c = fmaxf(coord, 0.0f);
    int low0 = (int)floorf(c);
    bool cap = low0 >= limit - 1;
    lo = cap ? limit - 1 : low0;
    hi = cap ? limit - 1 : low0 + 1;
    c = cap ? (float)lo : c;
    float l = c - (float)lo;
    w1 = l * valid;
    w0 = (1.0f - l) * valid;
}

__global__ void __launch_bounds__(256)
roi_align_fallback(const float* __restrict__ x, const float* __restrict__ rois,
                   float* __restrict__ out, int total) {
    int idx = blockIdx.x * blockDim.x + threadIdx.x;
    if (idx >= total) return;
    int pw = idx % PW;
    int ph = (idx / PW) % PH;
    int c  = (idx / (PW * PH)) % C_;
    int k  = idx / (PW * PH * C_);
    const float* r = rois + (size_t)k * 5;
    int b = (int)r[0];
    float start_w = r[1] * SCALE - 0.5f;
    float start_h = r[2] * SCALE - 0.5f;
    float bin_w = (r[3] * SCALE - 0.5f - start_w) / (float)PW;
    float bin_h = (r[4] * SCALE - 0.5f - start_h) / (float)PH;
    const float* xp = x + ((size_t)b * C_ + c) * (size_t)HW_;
    float acc = 0.0f;
#pragma unroll
    for (int sy = 0; sy < 2; ++sy) {
        float yc = start_h + ((float)ph + (sy + 0.5f) * 0.5f) * bin_h;
        int yl, yh; float wy0, wy1;
        axis_sample(yc, H_, yl, yh, wy0, wy1);
        const float* row0 = xp + (size_t)yl * W_;
        const float* row1 = xp + (size_t)yh * W_;
#pragma unroll
        for (int sx = 0; sx < 2; ++sx) {
            float xc2 = start_w + ((float)pw + (sx + 0.5f) * 0.5f) * bin_w;
            int xl, xh; float wx0, wx1;
            axis_sample(xc2, W_, xl, xh, wx0, wx1);
            acc += wy0 * (wx0 * row0[xl] + wx1 * row0[xh])
                 + wy1 * (wx0 * row1[xl] + wx1 * row1[xh]);
        }
    }
    out[idx] = acc * 0.25f;
}

extern "C" void kernel_launch(void* const* d_in, const int* in_sizes, int n_in,
                              void* d_out, int out_size, void* d_ws, size_t ws_size,
                              hipStream_t stream) {
    const float* x    = (const float*)d_in[0];
    const float* rois = (const float*)d_in[1];
    float* out = (float*)d_out;
    int K = in_sizes[1] / 5;

    size_t xtbytes = (size_t)2 * HW_ * C_ * sizeof(__hip_bfloat16);  // 40.96 MB
    size_t need = xtbytes + 4096 * sizeof(int);
    if (ws_size >= need && K <= 4096 && K >= 8) {
        __hip_bfloat16* xt = (__hip_bfloat16*)d_ws;
        int* perm = (int*)((char*)d_ws + xtbytes);
        int mode = (K % 4 == 0 && K <= 1024) ? 1 : 0;
        dim3 tgrid(HW_ / 64 + 1, C_ / 64, 2);   // +1: sort block
        dim3 tblock(64, 8);
        transpose_sort_kernel<<<tgrid, tblock, 0, stream>>>(x, xt, rois, K, mode, perm);
        roi_main<<<K * 2, 512, 0, stream>>>(xt, rois, perm, out, K, mode);
    } else {
        int total = K * C_ * PH * PW;
        roi_align_fallback<<<(total + 255) / 256, 256, 0, stream>>>(x, rois, out, total);
    }
}